// Round 5
// baseline (529.399 us; speedup 1.0000x reference)
//
#include <hip/hip_runtime.h>
#include <hip/hip_bf16.h>

// GraphConv x3 on MI355X.
//   1. Build CSR (by dst) on device each call: histogram -> 3-phase parallel
//      scan -> scatter. (graph-capture-safe; no fp32 atomics)
//   2. Per layer: aggregate via CSR (1 wave/node, float4 gathers, coalesced
//      writes), then fused dual-GEMM  out = agg@W_rel + h@W_root + b (+relu).
//   3. Layer 3: segsum(h2)@W_rel3 == segsum(h2@W_rel3) -> aggregate at 64-wide,
//      both transforms fused into one dual-output pass over h2.
// R1: parallel 3-phase scan (was 109 us single-block).
// R2: layer-3 GEMM fusion.
// R3: GEMMs rewritten no-LDS register-tiled, TM=8 nodes/thread: weight loads
//     amortized 4x better (was VALUBusy 38%, occ 31%, 46 TF; LDS cap removed).
// R4: resubmit of R3 (GPU unavailable that round; changes unmeasured).

#define N_D_IN 64
#define N_D_HID 128
#define N_D_OUT 64

// ---------------- int64-vs-int32 edge_index detection ----------------
__global__ void detect_kernel(const unsigned int* __restrict__ w, int* __restrict__ flag) {
    __shared__ int nonzero;
    if (threadIdx.x == 0) nonzero = 0;
    __syncthreads();
    for (int i = threadIdx.x; i < 1024; i += 256) {
        if (w[2 * i + 1] != 0u) atomicOr(&nonzero, 1);
    }
    __syncthreads();
    if (threadIdx.x == 0) *flag = (nonzero ? 0 : 1);  // 1 => int64 layout
}

__device__ __forceinline__ int load_edge(const void* edge, const int* flag, size_t idx) {
    if (*flag) return (int)((const long long*)edge)[idx];
    return ((const int*)edge)[idx];
}

// ---------------- CSR build ----------------
__global__ void hist_kernel(const void* __restrict__ edge, const int* __restrict__ flag,
                            int* __restrict__ cnt, int n_edges) {
    int i = blockIdx.x * 256 + threadIdx.x;
    if (i >= n_edges) return;
    int d = load_edge(edge, flag, (size_t)n_edges + i);  // dst
    atomicAdd(&cnt[d], 1);
}

__global__ __launch_bounds__(256) void blocksum_kernel(const int* __restrict__ cnt,
                                                       int* __restrict__ bsum, int n) {
    int i = blockIdx.x * 256 + threadIdx.x;
    int v = (i < n) ? cnt[i] : 0;
#pragma unroll
    for (int off = 1; off < 64; off <<= 1) v += __shfl_xor(v, off);
    __shared__ int wsums[4];
    if ((threadIdx.x & 63) == 0) wsums[threadIdx.x >> 6] = v;
    __syncthreads();
    if (threadIdx.x == 0) bsum[blockIdx.x] = wsums[0] + wsums[1] + wsums[2] + wsums[3];
}

__global__ __launch_bounds__(1024) void scan_bsum_kernel(const int* __restrict__ bsum,
                                                         int* __restrict__ boff, int nb) {
    __shared__ int tmp[1024];
    int t = threadIdx.x;
    int v = (t < nb) ? bsum[t] : 0;
    tmp[t] = v;
    __syncthreads();
    for (int off = 1; off < 1024; off <<= 1) {
        int u = (t >= off) ? tmp[t - off] : 0;
        __syncthreads();
        tmp[t] += u;
        __syncthreads();
    }
    if (t < nb) boff[t] = tmp[t] - v;  // exclusive
}

__global__ __launch_bounds__(256) void emit_kernel(const int* __restrict__ cnt,
                                                   const int* __restrict__ boff,
                                                   int* __restrict__ row_ptr,
                                                   int* __restrict__ cursor, int n) {
    __shared__ int tmp[256];
    int b = blockIdx.x, t = threadIdx.x;
    int i = b * 256 + t;
    int v = (i < n) ? cnt[i] : 0;
    tmp[t] = v;
    __syncthreads();
    for (int off = 1; off < 256; off <<= 1) {
        int u = (t >= off) ? tmp[t - off] : 0;
        __syncthreads();
        tmp[t] += u;
        __syncthreads();
    }
    int excl = tmp[t] - v + boff[b];
    if (i < n) {
        row_ptr[i] = excl;
        cursor[i] = excl;
        if (i == n - 1) row_ptr[n] = excl + v;
    }
}

__global__ void scatter_kernel(const void* __restrict__ edge, const int* __restrict__ flag,
                               int* __restrict__ cursor, int* __restrict__ srcs, int n_edges) {
    int i = blockIdx.x * 256 + threadIdx.x;
    if (i >= n_edges) return;
    int s = load_edge(edge, flag, (size_t)i);            // src
    int d = load_edge(edge, flag, (size_t)n_edges + i);  // dst
    int pos = atomicAdd(&cursor[d], 1);
    srcs[pos] = s;
}

// ---------------- CSR aggregation: 1 wave per node, 4 nodes/block ----------
template <int D, bool ADD_BASE>
__global__ __launch_bounds__(256) void agg_kernel(const float* __restrict__ in,
                                                  const float* __restrict__ base,
                                                  float* __restrict__ out,
                                                  const int* __restrict__ row_ptr,
                                                  const int* __restrict__ srcs, int n_nodes) {
    constexpr int LPR = D / 4;       // lanes per row: 16 (D=64) or 32 (D=128)
    constexpr int SLOTS = 64 / LPR;  // concurrent edges: 4 or 2
    const int node = blockIdx.x * 4 + (threadIdx.x >> 6);
    if (node >= n_nodes) return;
    const int lane = threadIdx.x & 63;
    const int c4 = lane % LPR;
    const int slot = lane / LPR;
    const int e0 = row_ptr[node], e1 = row_ptr[node + 1];
    float4 acc = make_float4(0.f, 0.f, 0.f, 0.f);
    for (int e = e0 + slot; e < e1; e += SLOTS) {
        int s = srcs[e];
        float4 v = *(const float4*)&in[(size_t)s * D + c4 * 4];
        acc.x += v.x; acc.y += v.y; acc.z += v.z; acc.w += v.w;
    }
#pragma unroll
    for (int off = LPR; off < 64; off <<= 1) {
        acc.x += __shfl_xor(acc.x, off);
        acc.y += __shfl_xor(acc.y, off);
        acc.z += __shfl_xor(acc.z, off);
        acc.w += __shfl_xor(acc.w, off);
    }
    if (lane < LPR) {
        if (ADD_BASE) {
            float4 b = *(const float4*)&base[(size_t)node * D + c4 * 4];
            acc.x += b.x; acc.y += b.y; acc.z += b.z; acc.w += b.w;
        }
        *(float4*)&out[(size_t)node * D + c4 * 4] = acc;
    }
}

// ------- no-LDS register-tiled node GEMM: out = A@W1 (+B@W2) (+b) (+relu) ---
// 256 threads; JS = DOUT/4 j-slots of 4 channels; TM nodes per thread.
// A/B row loads are wave-broadcast (same addr across JS lanes -> 1 L1 txn);
// weight loads amortize over TM nodes. No LDS, no syncs.
template <int DIN, int DOUT, int TM, bool DUAL, bool RELU, bool BIAS>
__global__ __launch_bounds__(256) void gemm_kernel(const float* __restrict__ A,
                                                   const float* __restrict__ B,
                                                   const float* __restrict__ W1,
                                                   const float* __restrict__ W2,
                                                   const float* __restrict__ bias,
                                                   float* __restrict__ out, int n_nodes) {
    constexpr int JS = DOUT / 4;
    constexpr int NL = 256 / JS;
    constexpr int BN = NL * TM;
    constexpr int K4 = DIN / 4;

    const int tid = threadIdx.x;
    const int j0 = (tid % JS) * 4;
    const int n0 = blockIdx.x * BN + (tid / JS) * TM;

    size_t arow[TM];
#pragma unroll
    for (int m = 0; m < TM; ++m) {
        int n = n0 + m;
        if (n > n_nodes - 1) n = n_nodes - 1;  // clamp loads; stores guarded
        arow[m] = (size_t)n * DIN * 4;
    }

    float acc[TM][4];
#pragma unroll
    for (int m = 0; m < TM; ++m)
#pragma unroll
        for (int c = 0; c < 4; ++c) acc[m][c] = 0.f;

#pragma unroll 4
    for (int k4 = 0; k4 < K4; ++k4) {
        float w1s[4][4], w2s[4][4];
#pragma unroll
        for (int u = 0; u < 4; ++u) {
            float4 t = *(const float4*)&W1[(size_t)(k4 * 4 + u) * DOUT + j0];
            w1s[u][0] = t.x; w1s[u][1] = t.y; w1s[u][2] = t.z; w1s[u][3] = t.w;
            if constexpr (DUAL) {
                float4 t2 = *(const float4*)&W2[(size_t)(k4 * 4 + u) * DOUT + j0];
                w2s[u][0] = t2.x; w2s[u][1] = t2.y; w2s[u][2] = t2.z; w2s[u][3] = t2.w;
            }
        }
#pragma unroll
        for (int m = 0; m < TM; ++m) {
            float4 a4 = *(const float4*)((const char*)A + arow[m] + (size_t)k4 * 16);
            float av[4] = {a4.x, a4.y, a4.z, a4.w};
#pragma unroll
            for (int c = 0; c < 4; ++c)
#pragma unroll
                for (int u = 0; u < 4; ++u) acc[m][c] += av[u] * w1s[u][c];
            if constexpr (DUAL) {
                float4 b4 = *(const float4*)((const char*)B + arow[m] + (size_t)k4 * 16);
                float bv4[4] = {b4.x, b4.y, b4.z, b4.w};
#pragma unroll
                for (int c = 0; c < 4; ++c)
#pragma unroll
                    for (int u = 0; u < 4; ++u) acc[m][c] += bv4[u] * w2s[u][c];
            }
        }
    }

    float bv[4] = {0.f, 0.f, 0.f, 0.f};
    if constexpr (BIAS) {
        float4 t = *(const float4*)&bias[j0];
        bv[0] = t.x; bv[1] = t.y; bv[2] = t.z; bv[3] = t.w;
    }
#pragma unroll
    for (int m = 0; m < TM; ++m) {
        int gn = n0 + m;
        if (gn < n_nodes) {
            float v0 = acc[m][0] + bv[0], v1 = acc[m][1] + bv[1];
            float v2 = acc[m][2] + bv[2], v3 = acc[m][3] + bv[3];
            if constexpr (RELU) {
                v0 = fmaxf(v0, 0.f); v1 = fmaxf(v1, 0.f);
                v2 = fmaxf(v2, 0.f); v3 = fmaxf(v3, 0.f);
            }
            float4 o; o.x = v0; o.y = v1; o.z = v2; o.w = v3;
            *(float4*)&out[(size_t)gn * DOUT + j0] = o;
        }
    }
}

// ---- layer-3 dual-OUTPUT GEMM (no-LDS): o1 = A@W1, o2 = A@W2 + bias -------
template <int DIN, int DOUT, int TM>
__global__ __launch_bounds__(256) void gemm2out_kernel(const float* __restrict__ A,
                                                       const float* __restrict__ W1,
                                                       const float* __restrict__ W2,
                                                       const float* __restrict__ bias,
                                                       float* __restrict__ o1,
                                                       float* __restrict__ o2, int n_nodes) {
    constexpr int JS = DOUT / 4;
    constexpr int NL = 256 / JS;
    constexpr int BN = NL * TM;
    constexpr int K4 = DIN / 4;

    const int tid = threadIdx.x;
    const int j0 = (tid % JS) * 4;
    const int n0 = blockIdx.x * BN + (tid / JS) * TM;

    size_t arow[TM];
#pragma unroll
    for (int m = 0; m < TM; ++m) {
        int n = n0 + m;
        if (n > n_nodes - 1) n = n_nodes - 1;
        arow[m] = (size_t)n * DIN * 4;
    }

    float acc1[TM][4], acc2[TM][4];
#pragma unroll
    for (int m = 0; m < TM; ++m)
#pragma unroll
        for (int c = 0; c < 4; ++c) { acc1[m][c] = 0.f; acc2[m][c] = 0.f; }

#pragma unroll 4
    for (int k4 = 0; k4 < K4; ++k4) {
        float w1s[4][4], w2s[4][4];
#pragma unroll
        for (int u = 0; u < 4; ++u) {
            float4 t = *(const float4*)&W1[(size_t)(k4 * 4 + u) * DOUT + j0];
            w1s[u][0] = t.x; w1s[u][1] = t.y; w1s[u][2] = t.z; w1s[u][3] = t.w;
            float4 t2 = *(const float4*)&W2[(size_t)(k4 * 4 + u) * DOUT + j0];
            w2s[u][0] = t2.x; w2s[u][1] = t2.y; w2s[u][2] = t2.z; w2s[u][3] = t2.w;
        }
#pragma unroll
        for (int m = 0; m < TM; ++m) {
            float4 a4 = *(const float4*)((const char*)A + arow[m] + (size_t)k4 * 16);
            float av[4] = {a4.x, a4.y, a4.z, a4.w};
#pragma unroll
            for (int c = 0; c < 4; ++c)
#pragma unroll
                for (int u = 0; u < 4; ++u) {
                    acc1[m][c] += av[u] * w1s[u][c];
                    acc2[m][c] += av[u] * w2s[u][c];
                }
        }
    }

    float4 bt = *(const float4*)&bias[j0];
    float bv[4] = {bt.x, bt.y, bt.z, bt.w};
#pragma unroll
    for (int m = 0; m < TM; ++m) {
        int gn = n0 + m;
        if (gn < n_nodes) {
            float4 q;
            q.x = acc1[m][0]; q.y = acc1[m][1]; q.z = acc1[m][2]; q.w = acc1[m][3];
            *(float4*)&o1[(size_t)gn * DOUT + j0] = q;
            float4 r;
            r.x = acc2[m][0] + bv[0]; r.y = acc2[m][1] + bv[1];
            r.z = acc2[m][2] + bv[2]; r.w = acc2[m][3] + bv[3];
            *(float4*)&o2[(size_t)gn * DOUT + j0] = r;
        }
    }
}

extern "C" void kernel_launch(void* const* d_in, const int* in_sizes, int n_in,
                              void* d_out, int out_size, void* d_ws, size_t ws_size,
                              hipStream_t stream) {
    const float* x = (const float*)d_in[0];
    const void* edge = d_in[1];
    const float* w_rel1 = (const float*)d_in[2];
    const float* w_root1 = (const float*)d_in[3];
    const float* b1 = (const float*)d_in[4];
    const float* w_rel2 = (const float*)d_in[5];
    const float* w_root2 = (const float*)d_in[6];
    const float* b2 = (const float*)d_in[7];
    const float* w_rel3 = (const float*)d_in[8];
    const float* w_root3 = (const float*)d_in[9];
    const float* b3 = (const float*)d_in[10];
    float* out = (float*)d_out;

    const int n_nodes = in_sizes[0] / N_D_IN;  // 50000
    const int n_edges = in_sizes[1] / 2;       // 800000

    char* ws = (char*)d_ws;
    int* cnt = (int*)(ws + 0);
    int* row_ptr = (int*)(ws + (1 << 20));
    int* cursor = (int*)(ws + (2 << 20));
    int* flag = (int*)(ws + (3 << 20));
    int* bsum = (int*)(ws + (3 << 20) + 1024);
    int* boff = (int*)(ws + (3 << 20) + 1024 + 4096);
    int* srcs = (int*)(ws + (4 << 20));
    float* agg = (float*)(ws + (size_t)(8 << 20));
    float* h1 = (float*)(ws + (size_t)(34 << 20));
    float* h2 = (float*)(ws + (size_t)(60 << 20));
    float* t3 = (float*)(ws + (size_t)(34 << 20));     // reuse h1 (dead by then)
    float* base3 = (float*)(ws + (size_t)(47 << 20));  // reuse h1 area +13MiB

    const int eblk = (n_edges + 255) / 256;
    const int nblk = (n_nodes + 255) / 256;  // 196 <= 1024
    const int ablk = (n_nodes + 3) / 4;

    hipMemsetAsync(cnt, 0, (size_t)n_nodes * sizeof(int), stream);
    detect_kernel<<<1, 256, 0, stream>>>((const unsigned int*)edge, flag);
    hist_kernel<<<eblk, 256, 0, stream>>>(edge, flag, cnt, n_edges);
    blocksum_kernel<<<nblk, 256, 0, stream>>>(cnt, bsum, n_nodes);
    scan_bsum_kernel<<<1, 1024, 0, stream>>>(bsum, boff, nblk);
    emit_kernel<<<nblk, 256, 0, stream>>>(cnt, boff, row_ptr, cursor, n_nodes);
    scatter_kernel<<<eblk, 256, 0, stream>>>(edge, flag, cursor, srcs, n_edges);

    // GEMM grids: BN = (256/(DOUT/4)) * TM nodes per block
    const int g128 = (n_nodes + 63) / 64;   // DOUT=128, TM=8 -> BN=64
    const int g64 = (n_nodes + 63) / 64;    // DOUT=64,  TM=4 -> BN=64

    // Layer 1: agg(x)@Wr1 + x@Wo1 + b1, relu
    agg_kernel<64, false><<<ablk, 256, 0, stream>>>(x, nullptr, agg, row_ptr, srcs, n_nodes);
    gemm_kernel<64, 128, 8, true, true, true><<<g128, 256, 0, stream>>>(
        agg, x, w_rel1, w_root1, b1, h1, n_nodes);

    // Layer 2: agg(h1)@Wr2 + h1@Wo2 + b2, relu
    agg_kernel<128, false><<<ablk, 256, 0, stream>>>(h1, nullptr, agg, row_ptr, srcs, n_nodes);
    gemm_kernel<128, 128, 8, true, true, true><<<g128, 256, 0, stream>>>(
        agg, h1, w_rel2, w_root2, b2, h2, n_nodes);

    // Layer 3: out = segsum(h2@Wr3) + h2@Wo3 + b3
    gemm2out_kernel<128, 64, 4><<<g64, 256, 0, stream>>>(
        h2, w_rel3, w_root3, b3, t3, base3, n_nodes);
    agg_kernel<64, true><<<ablk, 256, 0, stream>>>(t3, base3, out, row_ptr, srcs, n_nodes);
}

// Round 8
// 450.359 us; speedup vs baseline: 1.1755x; 1.1755x over previous
//
#include <hip/hip_runtime.h>
#include <hip/hip_bf16.h>

// GraphConv x3 on MI355X.
//   1. Build CSR (by dst) on device each call: histogram -> 3-phase parallel
//      scan -> scatter. (graph-capture-safe; no fp32 atomics)
//   2. Per layer: aggregate via CSR (1 wave/node, float4 gathers, coalesced
//      writes), then fused dual-GEMM  out = agg@W_rel + h@W_root + b (+relu).
//   3. Layer 3: segsum(h2)@W_rel3 == segsum(h2@W_rel3) -> aggregate at 64-wide,
//      both transforms fused into one dual-output pass over h2.
// R1: parallel 3-phase scan (was 109 us single-block).
// R2: layer-3 GEMM fusion. GEMM w/ LDS A/B: 71us, VALUBusy 38% (weight-load
//     stall: 8 node-lane groups redundantly stream 128KB weights via L1/L2).
// R3/R4: no-LDS GEMM -> REGRESSED 133us (VALUBusy 19%: global A/B latency,
//     76 VGPR, no pipelining). Reverted.
// R5: k-tiled LDS GEMM: A-tile + B-tile + W1/W2 k-slices ALL in LDS (40KB).
//     Weights fetched once per block cooperatively; inner loop is LDS
//     broadcast + FMA. Predicted VALU-bound ~35-45us for layer 2.
// R6/R7: resubmits of R5 (GPU unavailable both rounds; still unmeasured).

#define N_D_IN 64
#define N_D_HID 128
#define N_D_OUT 64

// ---------------- int64-vs-int32 edge_index detection ----------------
__global__ void detect_kernel(const unsigned int* __restrict__ w, int* __restrict__ flag) {
    __shared__ int nonzero;
    if (threadIdx.x == 0) nonzero = 0;
    __syncthreads();
    for (int i = threadIdx.x; i < 1024; i += 256) {
        if (w[2 * i + 1] != 0u) atomicOr(&nonzero, 1);
    }
    __syncthreads();
    if (threadIdx.x == 0) *flag = (nonzero ? 0 : 1);  // 1 => int64 layout
}

__device__ __forceinline__ int load_edge(const void* edge, const int* flag, size_t idx) {
    if (*flag) return (int)((const long long*)edge)[idx];
    return ((const int*)edge)[idx];
}

// ---------------- CSR build ----------------
__global__ void hist_kernel(const void* __restrict__ edge, const int* __restrict__ flag,
                            int* __restrict__ cnt, int n_edges) {
    int i = blockIdx.x * 256 + threadIdx.x;
    if (i >= n_edges) return;
    int d = load_edge(edge, flag, (size_t)n_edges + i);  // dst
    atomicAdd(&cnt[d], 1);
}

__global__ __launch_bounds__(256) void blocksum_kernel(const int* __restrict__ cnt,
                                                       int* __restrict__ bsum, int n) {
    int i = blockIdx.x * 256 + threadIdx.x;
    int v = (i < n) ? cnt[i] : 0;
#pragma unroll
    for (int off = 1; off < 64; off <<= 1) v += __shfl_xor(v, off);
    __shared__ int wsums[4];
    if ((threadIdx.x & 63) == 0) wsums[threadIdx.x >> 6] = v;
    __syncthreads();
    if (threadIdx.x == 0) bsum[blockIdx.x] = wsums[0] + wsums[1] + wsums[2] + wsums[3];
}

__global__ __launch_bounds__(1024) void scan_bsum_kernel(const int* __restrict__ bsum,
                                                         int* __restrict__ boff, int nb) {
    __shared__ int tmp[1024];
    int t = threadIdx.x;
    int v = (t < nb) ? bsum[t] : 0;
    tmp[t] = v;
    __syncthreads();
    for (int off = 1; off < 1024; off <<= 1) {
        int u = (t >= off) ? tmp[t - off] : 0;
        __syncthreads();
        tmp[t] += u;
        __syncthreads();
    }
    if (t < nb) boff[t] = tmp[t] - v;  // exclusive
}

__global__ __launch_bounds__(256) void emit_kernel(const int* __restrict__ cnt,
                                                   const int* __restrict__ boff,
                                                   int* __restrict__ row_ptr,
                                                   int* __restrict__ cursor, int n) {
    __shared__ int tmp[256];
    int b = blockIdx.x, t = threadIdx.x;
    int i = b * 256 + t;
    int v = (i < n) ? cnt[i] : 0;
    tmp[t] = v;
    __syncthreads();
    for (int off = 1; off < 256; off <<= 1) {
        int u = (t >= off) ? tmp[t - off] : 0;
        __syncthreads();
        tmp[t] += u;
        __syncthreads();
    }
    int excl = tmp[t] - v + boff[b];
    if (i < n) {
        row_ptr[i] = excl;
        cursor[i] = excl;
        if (i == n - 1) row_ptr[n] = excl + v;
    }
}

__global__ void scatter_kernel(const void* __restrict__ edge, const int* __restrict__ flag,
                               int* __restrict__ cursor, int* __restrict__ srcs, int n_edges) {
    int i = blockIdx.x * 256 + threadIdx.x;
    if (i >= n_edges) return;
    int s = load_edge(edge, flag, (size_t)i);            // src
    int d = load_edge(edge, flag, (size_t)n_edges + i);  // dst
    int pos = atomicAdd(&cursor[d], 1);
    srcs[pos] = s;
}

// ---------------- CSR aggregation: 1 wave per node, 4 nodes/block ----------
template <int D, bool ADD_BASE>
__global__ __launch_bounds__(256) void agg_kernel(const float* __restrict__ in,
                                                  const float* __restrict__ base,
                                                  float* __restrict__ out,
                                                  const int* __restrict__ row_ptr,
                                                  const int* __restrict__ srcs, int n_nodes) {
    constexpr int LPR = D / 4;       // lanes per row: 16 (D=64) or 32 (D=128)
    constexpr int SLOTS = 64 / LPR;  // concurrent edges: 4 or 2
    const int node = blockIdx.x * 4 + (threadIdx.x >> 6);
    if (node >= n_nodes) return;
    const int lane = threadIdx.x & 63;
    const int c4 = lane % LPR;
    const int slot = lane / LPR;
    const int e0 = row_ptr[node], e1 = row_ptr[node + 1];
    float4 acc = make_float4(0.f, 0.f, 0.f, 0.f);
    for (int e = e0 + slot; e < e1; e += SLOTS) {
        int s = srcs[e];
        float4 v = *(const float4*)&in[(size_t)s * D + c4 * 4];
        acc.x += v.x; acc.y += v.y; acc.z += v.z; acc.w += v.w;
    }
#pragma unroll
    for (int off = LPR; off < 64; off <<= 1) {
        acc.x += __shfl_xor(acc.x, off);
        acc.y += __shfl_xor(acc.y, off);
        acc.z += __shfl_xor(acc.z, off);
        acc.w += __shfl_xor(acc.w, off);
    }
    if (lane < LPR) {
        if (ADD_BASE) {
            float4 b = *(const float4*)&base[(size_t)node * D + c4 * 4];
            acc.x += b.x; acc.y += b.y; acc.z += b.z; acc.w += b.w;
        }
        *(float4*)&out[(size_t)node * D + c4 * 4] = acc;
    }
}

// -------- k-tiled all-LDS GEMM ---------------------------------------------
// MODE 1 (dual-in):  o1 = A@W1 + B@W2 + bias  (+relu)
// MODE 2 (dual-out): o1 = A@W1 ; o2 = A@W2 + bias
// 256 threads, BN=32 nodes/block, k-tile KT=32. Per tile: stage A (+B) and
// the W1/W2 k-slices into LDS cooperatively (coalesced float4), then
// FMA from LDS (weight reads broadcast across node-lanes).
template <int DIN, int DOUT, int MODE, bool RELU>
__global__ __launch_bounds__(256) void gemm_tiled(const float* __restrict__ A,
                                                  const float* __restrict__ B,
                                                  const float* __restrict__ W1,
                                                  const float* __restrict__ W2,
                                                  const float* __restrict__ bias,
                                                  float* __restrict__ o1,
                                                  float* __restrict__ o2, int n_nodes) {
    constexpr int BN = 32;
    constexpr int KT = 32;
    constexpr int JS = DOUT / 4;            // 32 (DOUT=128) or 16 (DOUT=64)
    constexpr int NL = 256 / JS;            // 8 or 16
    constexpr int TM = BN / NL;             // 4 or 2
    constexpr int NKT = DIN / KT;           // 2 (DIN=64) or 4 (DIN=128)
    constexpr int K4T = KT / 4;             // 8
    constexpr int W4 = (KT * DOUT / 4) / 256;  // float4 loads/thread per W: 4 or 2

    __shared__ float sA[BN][KT];
    __shared__ float sB[(MODE == 1) ? BN : 1][(MODE == 1) ? KT : 4];
    __shared__ float sW1[KT][DOUT];
    __shared__ float sW2[KT][DOUT];

    const int tid = threadIdx.x;
    const int node0 = blockIdx.x * BN;
    const int jslot = tid % JS;
    const int j0 = jslot * 4;
    const int nlane = tid / JS;

    float acc1[TM][4];
    float acc2[(MODE == 2) ? TM : 1][4];
#pragma unroll
    for (int m = 0; m < TM; ++m)
#pragma unroll
        for (int c = 0; c < 4; ++c) {
            acc1[m][c] = 0.f;
            if constexpr (MODE == 2) acc2[m][c] = 0.f;
        }

    for (int kt = 0; kt < NKT; ++kt) {
        // ---- stage A (+B): BN*KT = 1024 floats = 256 x float4, coalesced
        {
            int n = tid / K4T, c4 = tid % K4T;
            int gn = node0 + n;
            float4 av = make_float4(0.f, 0.f, 0.f, 0.f);
            float4 bv = make_float4(0.f, 0.f, 0.f, 0.f);
            if (gn < n_nodes) {
                av = *(const float4*)&A[(size_t)gn * DIN + kt * KT + c4 * 4];
                if constexpr (MODE == 1)
                    bv = *(const float4*)&B[(size_t)gn * DIN + kt * KT + c4 * 4];
            }
            *(float4*)&sA[n][c4 * 4] = av;
            if constexpr (MODE == 1) *(float4*)&sB[n][c4 * 4] = bv;
        }
        // ---- stage W1/W2 k-slices: KT*DOUT floats each, coalesced
#pragma unroll
        for (int w = 0; w < W4; ++w) {
            int idx = w * 256 + tid;
            int r = idx / (DOUT / 4), c4 = idx % (DOUT / 4);
            *(float4*)&sW1[r][c4 * 4] =
                *(const float4*)&W1[(size_t)(kt * KT + r) * DOUT + c4 * 4];
            *(float4*)&sW2[r][c4 * 4] =
                *(const float4*)&W2[(size_t)(kt * KT + r) * DOUT + c4 * 4];
        }
        __syncthreads();

        // ---- compute: per k4, weights broadcast from LDS, A/B rows from LDS
#pragma unroll
        for (int k4 = 0; k4 < K4T; ++k4) {
            float w1s[4][4], w2s[4][4];
#pragma unroll
            for (int u = 0; u < 4; ++u) {
                float4 t = *(const float4*)&sW1[k4 * 4 + u][j0];
                w1s[u][0] = t.x; w1s[u][1] = t.y; w1s[u][2] = t.z; w1s[u][3] = t.w;
                float4 t2 = *(const float4*)&sW2[k4 * 4 + u][j0];
                w2s[u][0] = t2.x; w2s[u][1] = t2.y; w2s[u][2] = t2.z; w2s[u][3] = t2.w;
            }
#pragma unroll
            for (int m = 0; m < TM; ++m) {
                int n = nlane * TM + m;
                float4 a4 = *(const float4*)&sA[n][k4 * 4];
                float av[4] = {a4.x, a4.y, a4.z, a4.w};
                if constexpr (MODE == 1) {
                    float4 b4 = *(const float4*)&sB[n][k4 * 4];
                    float bv4[4] = {b4.x, b4.y, b4.z, b4.w};
#pragma unroll
                    for (int c = 0; c < 4; ++c)
#pragma unroll
                        for (int u = 0; u < 4; ++u)
                            acc1[m][c] += av[u] * w1s[u][c] + bv4[u] * w2s[u][c];
                } else {
#pragma unroll
                    for (int c = 0; c < 4; ++c)
#pragma unroll
                        for (int u = 0; u < 4; ++u) {
                            acc1[m][c] += av[u] * w1s[u][c];
                            acc2[m][c] += av[u] * w2s[u][c];
                        }
                }
            }
        }
        __syncthreads();
    }

    float4 bt = *(const float4*)&bias[j0];
    float bv[4] = {bt.x, bt.y, bt.z, bt.w};
#pragma unroll
    for (int m = 0; m < TM; ++m) {
        int gn = node0 + nlane * TM + m;
        if (gn < n_nodes) {
            if constexpr (MODE == 1) {
                float v0 = acc1[m][0] + bv[0], v1 = acc1[m][1] + bv[1];
                float v2 = acc1[m][2] + bv[2], v3 = acc1[m][3] + bv[3];
                if constexpr (RELU) {
                    v0 = fmaxf(v0, 0.f); v1 = fmaxf(v1, 0.f);
                    v2 = fmaxf(v2, 0.f); v3 = fmaxf(v3, 0.f);
                }
                float4 o; o.x = v0; o.y = v1; o.z = v2; o.w = v3;
                *(float4*)&o1[(size_t)gn * DOUT + j0] = o;
            } else {
                float4 q;
                q.x = acc1[m][0]; q.y = acc1[m][1]; q.z = acc1[m][2]; q.w = acc1[m][3];
                *(float4*)&o1[(size_t)gn * DOUT + j0] = q;
                float4 r;
                r.x = acc2[m][0] + bv[0]; r.y = acc2[m][1] + bv[1];
                r.z = acc2[m][2] + bv[2]; r.w = acc2[m][3] + bv[3];
                *(float4*)&o2[(size_t)gn * DOUT + j0] = r;
            }
        }
    }
}

extern "C" void kernel_launch(void* const* d_in, const int* in_sizes, int n_in,
                              void* d_out, int out_size, void* d_ws, size_t ws_size,
                              hipStream_t stream) {
    const float* x = (const float*)d_in[0];
    const void* edge = d_in[1];
    const float* w_rel1 = (const float*)d_in[2];
    const float* w_root1 = (const float*)d_in[3];
    const float* b1 = (const float*)d_in[4];
    const float* w_rel2 = (const float*)d_in[5];
    const float* w_root2 = (const float*)d_in[6];
    const float* b2 = (const float*)d_in[7];
    const float* w_rel3 = (const float*)d_in[8];
    const float* w_root3 = (const float*)d_in[9];
    const float* b3 = (const float*)d_in[10];
    float* out = (float*)d_out;

    const int n_nodes = in_sizes[0] / N_D_IN;  // 50000
    const int n_edges = in_sizes[1] / 2;       // 800000

    char* ws = (char*)d_ws;
    int* cnt = (int*)(ws + 0);
    int* row_ptr = (int*)(ws + (1 << 20));
    int* cursor = (int*)(ws + (2 << 20));
    int* flag = (int*)(ws + (3 << 20));
    int* bsum = (int*)(ws + (3 << 20) + 1024);
    int* boff = (int*)(ws + (3 << 20) + 1024 + 4096);
    int* srcs = (int*)(ws + (4 << 20));
    float* agg = (float*)(ws + (size_t)(8 << 20));
    float* h1 = (float*)(ws + (size_t)(34 << 20));
    float* h2 = (float*)(ws + (size_t)(60 << 20));
    float* t3 = (float*)(ws + (size_t)(34 << 20));     // reuse h1 (dead by then)
    float* base3 = (float*)(ws + (size_t)(47 << 20));  // reuse h1 area +13MiB

    const int eblk = (n_edges + 255) / 256;
    const int nblk = (n_nodes + 255) / 256;  // 196 <= 1024
    const int ablk = (n_nodes + 3) / 4;
    const int gblk = (n_nodes + 31) / 32;    // BN=32

    hipMemsetAsync(cnt, 0, (size_t)n_nodes * sizeof(int), stream);
    detect_kernel<<<1, 256, 0, stream>>>((const unsigned int*)edge, flag);
    hist_kernel<<<eblk, 256, 0, stream>>>(edge, flag, cnt, n_edges);
    blocksum_kernel<<<nblk, 256, 0, stream>>>(cnt, bsum, n_nodes);
    scan_bsum_kernel<<<1, 1024, 0, stream>>>(bsum, boff, nblk);
    emit_kernel<<<nblk, 256, 0, stream>>>(cnt, boff, row_ptr, cursor, n_nodes);
    scatter_kernel<<<eblk, 256, 0, stream>>>(edge, flag, cursor, srcs, n_edges);

    // Layer 1: agg(x)@Wr1 + x@Wo1 + b1, relu
    agg_kernel<64, false><<<ablk, 256, 0, stream>>>(x, nullptr, agg, row_ptr, srcs, n_nodes);
    gemm_tiled<64, 128, 1, true><<<gblk, 256, 0, stream>>>(
        agg, x, w_rel1, w_root1, b1, h1, nullptr, n_nodes);

    // Layer 2: agg(h1)@Wr2 + h1@Wo2 + b2, relu
    agg_kernel<128, false><<<ablk, 256, 0, stream>>>(h1, nullptr, agg, row_ptr, srcs, n_nodes);
    gemm_tiled<128, 128, 1, true><<<gblk, 256, 0, stream>>>(
        agg, h1, w_rel2, w_root2, b2, h2, nullptr, n_nodes);

    // Layer 3: out = segsum(h2@Wr3) + h2@Wo3 + b3  (dual-output pass over h2)
    gemm_tiled<128, 64, 2, false><<<gblk, 256, 0, stream>>>(
        h2, nullptr, w_rel3, w_root3, b3, t3, base3, n_nodes);
    agg_kernel<64, true><<<ablk, 256, 0, stream>>>(t3, base3, out, row_ptr, srcs, n_nodes);
}